// Round 2
// baseline (3090.221 us; speedup 1.0000x reference)
//
#include <hip/hip_runtime.h>
#include <hip/hip_bf16.h>
#include <hip/hip_fp16.h>

constexpr int INC  = 32;
constexpr int OUTC = 32;

// Chunked output-stationary path parameters.
constexpr int CHROWS     = 256;  // output rows per chunk (power of 2)
constexpr int CAP        = 384;  // records per (chunk,k) bucket: mean 256 + 8 sigma
constexpr int LDS_STRIDE = 33;   // padded fp32 row stride (dwords) -> bank-spread

typedef __bf16 bf16x8 __attribute__((ext_vector_type(8)));
typedef float  f32x4  __attribute__((ext_vector_type(4)));

// ---------------------------------------------------------------------------
// R5 theory: R2/R3/R4 triangulate a memory-side ATOMIC BYTE wall at
// ~1.1-1.2 TB/s (device-scope RMWs service past the non-coherent XCD L2s).
// Op-count halving (R4 u64 digits) made it slower. Fix = restructure:
//   pass 1: bin contribution records (iin | lrow<<19) into per-(chunk,k)
//           buckets. Atomics shrink to 10.8M u32 position counters.
//   pass 2: one block per 256-row chunk accumulates ALL 27 k-slices into an
//           LDS fp32 accumulator via ds_add_f32 (no global atomics, no
//           barriers in the k loop), then fused BN+ReLU streams out.
// ---------------------------------------------------------------------------

__global__ __launch_bounds__(256) void fill_records(
    const int* __restrict__ out_idx,   // [K][N]
    const int* __restrict__ in_idx,    // [K][N]
    unsigned*  __restrict__ head,      // [NB] zeroed
    unsigned*  __restrict__ records,   // [NB][CAP]
    int N, int K)
{
    const int k = blockIdx.y;
    const int* iout = out_idx + (size_t)k * N;
    const int* iin  = in_idx  + (size_t)k * N;
    for (int i = blockIdx.x * 256 + threadIdx.x; i < N; i += gridDim.x * 256) {
        const int orow = iout[i];
        const unsigned rec =
            (unsigned)iin[i] | ((unsigned)(orow & (CHROWS - 1)) << 19);
        const int b = (orow >> 8) * K + k;      // (chunk, k) bucket
        const unsigned pos = atomicAdd(head + b, 1u);
        if (pos < CAP)
            __builtin_nontemporal_store(rec, records + (size_t)b * CAP + pos);
    }
}

__global__ __launch_bounds__(512) void chunk_conv_mfma(
    const float* __restrict__ feats,    // [N][32]
    const float* __restrict__ wkern,    // [K][32][32]
    const unsigned* __restrict__ head,  // [NB] counts
    const unsigned* __restrict__ records,
    const float* __restrict__ gamma,
    const float* __restrict__ beta,
    const float* __restrict__ mean,
    const float* __restrict__ var,
    float* __restrict__ out,            // [N][32]
    int N, int K)
{
    __shared__ float acc[(CHROWS + 1) * LDS_STRIDE];   // +1 dump row for tails
    const int tid = threadIdx.x;
    for (int i = tid; i < (CHROWS + 1) * LDS_STRIDE; i += 512) acc[i] = 0.f;
    __syncthreads();

    const int c    = blockIdx.x;
    const int lane = tid & 63;
    const int col  = lane & 15;
    const int quad = lane >> 4;
    const int wid  = tid >> 6;          // 8 waves

    for (int k = 0; k < K; ++k) {
        const int b   = c * K + k;
        const int cnt = min((int)head[b], CAP);
        const unsigned* seg = records + (size_t)b * CAP;

        // B frags for W_k, column-permuted: acc0 -> ch 2*col, acc1 -> 2*col+1
        const float* wk = wkern + (size_t)k * (INC * OUTC);
        bf16x8 b0, b1;
#pragma unroll
        for (int j = 0; j < 8; ++j) {
            const int kk = quad * 8 + j;
            const float2 w2 = *(const float2*)(wk + kk * OUTC + 2 * col);
            b0[j] = (__bf16)w2.x;
            b1[j] = (__bf16)w2.y;
        }

        const int ntile = (cnt + 15) >> 4;
        for (int t = wid; t < ntile; t += 8) {
            const int s = t << 4;

            // A row for this lane = record s+col (masked to row 0 on tail)
            const unsigned ra = seg[s + col];
            const int iin = ((s + col) < cnt) ? (int)(ra & 0x7FFFFu) : 0;
            const float4* ap =
                (const float4*)(feats + (size_t)iin * INC + quad * 8);
            const float4 alo = ap[0];
            const float4 ahi = ap[1];
            bf16x8 a;
            a[0] = (__bf16)alo.x; a[1] = (__bf16)alo.y;
            a[2] = (__bf16)alo.z; a[3] = (__bf16)alo.w;
            a[4] = (__bf16)ahi.x; a[5] = (__bf16)ahi.y;
            a[6] = (__bf16)ahi.z; a[7] = (__bf16)ahi.w;

            // local rows for D rows quad*4+r (16B-aligned int4)
            const int4 rv = *(const int4*)(seg + s + quad * 4);

            f32x4 acc0 = {0.f, 0.f, 0.f, 0.f};
            f32x4 acc1 = {0.f, 0.f, 0.f, 0.f};
            acc0 = __builtin_amdgcn_mfma_f32_16x16x32_bf16(a, b0, acc0, 0, 0, 0);
            acc1 = __builtin_amdgcn_mfma_f32_16x16x32_bf16(a, b1, acc1, 0, 0, 0);

#pragma unroll
            for (int r = 0; r < 4; ++r) {
                const int idx  = s + quad * 4 + r;
                const int lrow = (idx < cnt)
                    ? (int)(((unsigned)rv[r] >> 19) & (CHROWS - 1))
                    : CHROWS;                          // dump row for tails
                unsafeAtomicAdd(&acc[lrow * LDS_STRIDE + 2 * col],     acc0[r]);
                unsafeAtomicAdd(&acc[lrow * LDS_STRIDE + 2 * col + 1], acc1[r]);
            }
        }
    }
    __syncthreads();

    // Fused BN + ReLU epilogue: thread -> (row group, 4-channel group)
    const int rr = tid >> 3;            // 0..63
    const int cp = (tid & 7) << 2;      // channel base 0,4,...,28
    float s0 = gamma[cp + 0] * rsqrtf(var[cp + 0] + 1e-5f);
    float s1 = gamma[cp + 1] * rsqrtf(var[cp + 1] + 1e-5f);
    float s2 = gamma[cp + 2] * rsqrtf(var[cp + 2] + 1e-5f);
    float s3 = gamma[cp + 3] * rsqrtf(var[cp + 3] + 1e-5f);
    float q0 = beta[cp + 0] - mean[cp + 0] * s0;
    float q1 = beta[cp + 1] - mean[cp + 1] * s1;
    float q2 = beta[cp + 2] - mean[cp + 2] * s2;
    float q3 = beta[cp + 3] - mean[cp + 3] * s3;

#pragma unroll
    for (int it = 0; it < CHROWS / 64; ++it) {
        const int row  = it * 64 + rr;
        const int grow = c * CHROWS + row;
        if (grow < N) {
            const float* ar = acc + row * LDS_STRIDE + cp;
            float4 o;
            o.x = fmaxf(fmaf(ar[0], s0, q0), 0.f);
            o.y = fmaxf(fmaf(ar[1], s1, q1), 0.f);
            o.z = fmaxf(fmaf(ar[2], s2, q2), 0.f);
            o.w = fmaxf(fmaf(ar[3], s3, q3), 0.f);
            *(float4*)(out + (size_t)grow * OUTC + cp) = o;
        }
    }
}

// ------------------- pk-f16 atomic path (R3 best, fallback) -----------------
__global__ __launch_bounds__(256) void scatter_conv_mfma_pk(
    const float* __restrict__ feats,
    const float* __restrict__ wkern,
    const int*   __restrict__ in_idx,
    const int*   __restrict__ out_idx,
    __half2*     __restrict__ ws,
    int N)
{
    const int k    = blockIdx.y;
    const int lane = threadIdx.x & 63;
    const int col  = lane & 15;
    const int quad = lane >> 4;

    const int wave   = blockIdx.x * 4 + (threadIdx.x >> 6);
    const int nwaves = gridDim.x * 4;

    const float* wk = wkern + (size_t)k * (INC * OUTC);
    bf16x8 b0, b1;
#pragma unroll
    for (int j = 0; j < 8; ++j) {
        const int kk = quad * 8 + j;
        b0[j] = (__bf16)wk[kk * OUTC + 2 * col];
        b1[j] = (__bf16)wk[kk * OUTC + 2 * col + 1];
    }

    const int* iin_p  = in_idx  + (size_t)k * N;
    const int* iout_p = out_idx + (size_t)k * N;
    const int  ntiles = N >> 4;

    for (int t = wave; t < ntiles; t += nwaves) {
        const int base = t << 4;
        const int iin = iin_p[base + col];
        int orow[4];
#pragma unroll
        for (int r = 0; r < 4; ++r) orow[r] = iout_p[base + quad * 4 + r];

        const float4* ap = (const float4*)(feats + (size_t)iin * INC + quad * 8);
        const float4 a_lo = ap[0];
        const float4 a_hi = ap[1];
        bf16x8 a;
        a[0] = (__bf16)a_lo.x; a[1] = (__bf16)a_lo.y;
        a[2] = (__bf16)a_lo.z; a[3] = (__bf16)a_lo.w;
        a[4] = (__bf16)a_hi.x; a[5] = (__bf16)a_hi.y;
        a[6] = (__bf16)a_hi.z; a[7] = (__bf16)a_hi.w;

        f32x4 acc0 = {0.f, 0.f, 0.f, 0.f};
        f32x4 acc1 = {0.f, 0.f, 0.f, 0.f};
        acc0 = __builtin_amdgcn_mfma_f32_16x16x32_bf16(a, b0, acc0, 0, 0, 0);
        acc1 = __builtin_amdgcn_mfma_f32_16x16x32_bf16(a, b1, acc1, 0, 0, 0);

#pragma unroll
        for (int r = 0; r < 4; ++r) {
            __half2 v = __halves2half2(__float2half(acc0[r]), __float2half(acc1[r]));
            unsafeAtomicAdd(ws + (size_t)orow[r] * 16 + col, v);
        }
    }
}

__global__ __launch_bounds__(256) void bn_relu_f16(
    const __half2* __restrict__ ws,
    float* __restrict__ out,
    const float* __restrict__ gamma,
    const float* __restrict__ beta,
    const float* __restrict__ mean,
    const float* __restrict__ var,
    int total2)
{
    const int tid    = blockIdx.x * blockDim.x + threadIdx.x;
    const int stride = gridDim.x * blockDim.x;
    const int p      = tid & 15;
    const int c0     = 2 * p;

    float s0 = gamma[c0]     * rsqrtf(var[c0]     + 1e-5f);
    float s1 = gamma[c0 + 1] * rsqrtf(var[c0 + 1] + 1e-5f);
    float q0 = beta[c0]     - mean[c0]     * s0;
    float q1 = beta[c0 + 1] - mean[c0 + 1] * s1;

    float2* po = (float2*)out;
    for (int i = tid; i < total2; i += stride) {
        const __half2 h = ws[i];
        float2 v;
        v.x = fmaxf(fmaf(__low2float(h),  s0, q0), 0.0f);
        v.y = fmaxf(fmaf(__high2float(h), s1, q1), 0.0f);
        po[i] = v;
    }
}

// ------------------------- fp32 fallback (R2 path) -------------------------
__global__ __launch_bounds__(256) void scatter_conv_mfma_f32(
    const float* __restrict__ feats,
    const float* __restrict__ wkern,
    const int*   __restrict__ in_idx,
    const int*   __restrict__ out_idx,
    float*       __restrict__ out,
    int N)
{
    const int k    = blockIdx.y;
    const int lane = threadIdx.x & 63;
    const int col  = lane & 15;
    const int quad = lane >> 4;
    const int wave   = blockIdx.x * 4 + (threadIdx.x >> 6);
    const int nwaves = gridDim.x * 4;

    const float* wk = wkern + (size_t)k * (INC * OUTC);
    bf16x8 b0, b1;
#pragma unroll
    for (int j = 0; j < 8; ++j) {
        const int kk = quad * 8 + j;
        b0[j] = (__bf16)wk[kk * OUTC + col];
        b1[j] = (__bf16)wk[kk * OUTC + 16 + col];
    }

    const int* iin_p  = in_idx  + (size_t)k * N;
    const int* iout_p = out_idx + (size_t)k * N;
    const int  ntiles = N >> 4;

    for (int t = wave; t < ntiles; t += nwaves) {
        const int base = t << 4;
        const int iin = iin_p[base + col];
        int orow[4];
#pragma unroll
        for (int r = 0; r < 4; ++r) orow[r] = iout_p[base + quad * 4 + r];

        const float4* ap = (const float4*)(feats + (size_t)iin * INC + quad * 8);
        const float4 a_lo = ap[0];
        const float4 a_hi = ap[1];
        bf16x8 a;
        a[0] = (__bf16)a_lo.x; a[1] = (__bf16)a_lo.y;
        a[2] = (__bf16)a_lo.z; a[3] = (__bf16)a_lo.w;
        a[4] = (__bf16)a_hi.x; a[5] = (__bf16)a_hi.y;
        a[6] = (__bf16)a_hi.z; a[7] = (__bf16)a_hi.w;

        f32x4 acc0 = {0.f, 0.f, 0.f, 0.f};
        f32x4 acc1 = {0.f, 0.f, 0.f, 0.f};
        acc0 = __builtin_amdgcn_mfma_f32_16x16x32_bf16(a, b0, acc0, 0, 0, 0);
        acc1 = __builtin_amdgcn_mfma_f32_16x16x32_bf16(a, b1, acc1, 0, 0, 0);

#pragma unroll
        for (int r = 0; r < 4; ++r) {
            float* dst = out + (size_t)orow[r] * OUTC + col;
            unsafeAtomicAdd(dst,      acc0[r]);
            unsafeAtomicAdd(dst + 16, acc1[r]);
        }
    }
}

__global__ __launch_bounds__(256) void bn_relu_f32_inplace(
    float* __restrict__ out,
    const float* __restrict__ gamma,
    const float* __restrict__ beta,
    const float* __restrict__ mean,
    const float* __restrict__ var,
    int total4)
{
    const int tid    = blockIdx.x * blockDim.x + threadIdx.x;
    const int stride = gridDim.x * blockDim.x;
    const int c0     = (tid & 7) << 2;

    float s[4], b[4];
#pragma unroll
    for (int j = 0; j < 4; ++j) {
        const int c = c0 + j;
        s[j] = gamma[c] * rsqrtf(var[c] + 1e-5f);
        b[j] = beta[c] - mean[c] * s[j];
    }

    float4* p = (float4*)out;
    for (int i = tid; i < total4; i += stride) {
        float4 v = p[i];
        v.x = fmaxf(fmaf(v.x, s[0], b[0]), 0.0f);
        v.y = fmaxf(fmaf(v.y, s[1], b[1]), 0.0f);
        v.z = fmaxf(fmaf(v.z, s[2], b[2]), 0.0f);
        v.w = fmaxf(fmaf(v.w, s[3], b[3]), 0.0f);
        p[i] = v;
    }
}

extern "C" void kernel_launch(void* const* d_in, const int* in_sizes, int n_in,
                              void* d_out, int out_size, void* d_ws, size_t ws_size,
                              hipStream_t stream) {
    const float* feats   = (const float*)d_in[0];
    const float* wkern   = (const float*)d_in[1];
    const float* gamma   = (const float*)d_in[2];
    const float* beta    = (const float*)d_in[3];
    const float* mean    = (const float*)d_in[4];
    const float* var     = (const float*)d_in[5];
    const int*   in_idx  = (const int*)d_in[6];
    const int*   out_idx = (const int*)d_in[7];
    float*       out     = (float*)d_out;

    const int N = in_sizes[0] / INC;                  // 400000
    const int K = in_sizes[1] / (INC * OUTC);         // 27

    const int NCH = (N + CHROWS - 1) / CHROWS;        // 1563 chunks
    const int NB  = NCH * K;                          // 42201 buckets
    const int head_words = (NB + 3) & ~3;             // 16B-align records
    const size_t need_new = ((size_t)head_words + (size_t)NB * CAP) * 4;  // ~65MB
    const size_t need_pk  = (size_t)N * OUTC * sizeof(__half);            // 25.6MB

    if (ws_size >= need_new && N <= (1 << 19)) {
        unsigned* head    = (unsigned*)d_ws;
        unsigned* records = head + head_words;
        hipMemsetAsync(head, 0, (size_t)NB * 4, stream);
        fill_records<<<dim3(256, K), 256, 0, stream>>>(
            out_idx, in_idx, head, records, N, K);
        chunk_conv_mfma<<<NCH, 512, 0, stream>>>(
            feats, wkern, head, records, gamma, beta, mean, var, out, N, K);
    } else if (ws_size >= need_pk) {
        __half2* acc = (__half2*)d_ws;
        hipMemsetAsync(acc, 0, need_pk, stream);
        dim3 grid(80, K);
        scatter_conv_mfma_pk<<<grid, 256, 0, stream>>>(
            feats, wkern, in_idx, out_idx, acc, N);
        bn_relu_f16<<<1024, 256, 0, stream>>>(acc, out, gamma, beta, mean, var, N * 16);
    } else {
        hipMemsetAsync(out, 0, (size_t)out_size * sizeof(float), stream);
        dim3 grid(80, K);
        scatter_conv_mfma_f32<<<grid, 256, 0, stream>>>(
            feats, wkern, in_idx, out_idx, out, N);
        bn_relu_f32_inplace<<<1024, 256, 0, stream>>>(
            out, gamma, beta, mean, var, out_size / 4);
    }
}

// Round 3
// 956.096 us; speedup vs baseline: 3.2321x; 3.2321x over previous
//
#include <hip/hip_runtime.h>
#include <hip/hip_bf16.h>
#include <hip/hip_fp16.h>

constexpr int INC  = 32;
constexpr int OUTC = 32;
constexpr int CAP_X      = 52224;  // per-(k,slice) records: mean 50000 + 10.6 sigma
constexpr int CTR_STRIDE = 16;     // pad counters to one 64B line each

typedef __bf16 bf16x8 __attribute__((ext_vector_type(8)));
typedef float  f32x4  __attribute__((ext_vector_type(4)));

// ---------------------------------------------------------------------------
// R6 theory: R2-R5 triangulate the wall = cross-XCD coherence point servicing
// ~1.2 TB/s of fine-grain RMW/store request bytes. ANY 10.8M-item random
// scatter (atomics OR 4B stores) costs 550-1000us. Fix: keep RMWs inside one
// XCD's L2:
//   - output rows partitioned into 8 slices; acc row = [8]xu64 = one 64B line
//     => each line atomically updated by exactly ONE XCD.
//   - blocks read their REAL XCD via s_getreg(HW_REG_XCC_ID) (m09) and
//     work-steal only their XCD's (k,slice) buckets => correctness does not
//     depend on block->XCD dispatch mapping.
//   - workgroup-scope u64 atomics (no cross-XCD coherence bit) execute in the
//     local L2. R4's verified 4-channel digit encode/decode reused.
//   - fill: 216 buckets only => wave-ballot aggregation: 1 counter atomic per
//     wave-group + CONTIGUOUS 8B-record runs (coalesced; no scatter wall).
//   - feats pre-converted to bf16 (25.6MB, L3-resident): halves gather bytes.
// ---------------------------------------------------------------------------

__device__ __forceinline__ unsigned lane_rank(unsigned long long m) {
    unsigned r = __builtin_amdgcn_mbcnt_lo((unsigned)m, 0u);
    return __builtin_amdgcn_mbcnt_hi((unsigned)(m >> 32), r);
}

__global__ __launch_bounds__(256) void prep_feats(
    const float* __restrict__ f, __bf16* __restrict__ fb, int total8)
{
    int i = blockIdx.x * 256 + threadIdx.x;
    const int stride = gridDim.x * 256;
    for (; i < total8; i += stride) {
        const float4* p = (const float4*)(f + (size_t)i * 8);
        const float4 a = p[0], b = p[1];
        bf16x8 v;
        v[0] = (__bf16)a.x; v[1] = (__bf16)a.y; v[2] = (__bf16)a.z; v[3] = (__bf16)a.w;
        v[4] = (__bf16)b.x; v[5] = (__bf16)b.y; v[6] = (__bf16)b.z; v[7] = (__bf16)b.w;
        *(bf16x8*)(fb + (size_t)i * 8) = v;
    }
}

// Bin (k,n) contributions into [K][8] buckets via wave-ballot aggregation.
__global__ __launch_bounds__(256) void fill_xcd(
    const int* __restrict__ in_idx, const int* __restrict__ out_idx,
    unsigned* __restrict__ head,     // [K*8] padded by CTR_STRIDE, zeroed
    uint2*    __restrict__ recs,     // [K*8][CAP_X] {iin, orow}
    int N, int slice)
{
    const int k = blockIdx.y;
    const int* iin_p  = in_idx  + (size_t)k * N;
    const int* iout_p = out_idx + (size_t)k * N;
    const int stride = gridDim.x * 256;
    const int nloop  = (N + stride - 1) / stride;
    int i = blockIdx.x * 256 + (int)threadIdx.x;
    for (int it = 0; it < nloop; ++it, i += stride) {
        const bool valid = i < N;
        int orow = 0, iin = 0;
        if (valid) { orow = iout_p[i]; iin = iin_p[i]; }
        const int sid = valid ? (orow / slice) : 8;
#pragma unroll 1
        for (int s = 0; s < 8; ++s) {
            const unsigned long long m = __ballot(sid == s);
            if (m == 0ull) continue;
            const int leader = (int)__ffsll((unsigned long long)m) - 1;
            unsigned base = 0;
            if ((int)(threadIdx.x & 63) == leader)
                base = atomicAdd(head + (size_t)(k * 8 + s) * CTR_STRIDE,
                                 (unsigned)__popcll(m));
            base = (unsigned)__shfl((int)base, leader);
            if (sid == s) {
                const unsigned pos = base + lane_rank(m);
                if (pos < CAP_X)
                    recs[(size_t)(k * 8 + s) * CAP_X + pos] =
                        make_uint2((unsigned)iin, (unsigned)orow);
            }
        }
    }
}

template<bool BF16F>
__global__ __launch_bounds__(256) void conv_xcd(
    const float*  __restrict__ feats,
    const __bf16* __restrict__ fbf,
    const float*  __restrict__ wkern,
    const unsigned* __restrict__ head,
    unsigned*       __restrict__ cursor,
    const uint2*    __restrict__ recs,
    unsigned long long* __restrict__ acc,   // [N][8] u64 digit lines (zeroed)
    int N, int K)
{
    const int lane = (int)(threadIdx.x & 63);
    const int col  = lane & 15;
    const int quad = lane >> 4;
    const int par  = col & 1;
    const int w    = col >> 1;
    // hwreg(HW_REG_XCC_ID=20, offset 0, size 32) -> imm 20 | (31<<11)
    const unsigned xcc = __builtin_amdgcn_s_getreg(20 | (31 << 11)) & 7u;
    const int kstart = (int)((blockIdx.x >> 3) % (unsigned)K);

    for (int kk = 0; kk < K; ++kk) {
        int k = kstart + kk; if (k >= K) k -= K;
        const int b = k * 8 + (int)xcc;
        const int cnt = min((int)head[(size_t)b * CTR_STRIDE], CAP_X);
        const int ntile = (cnt + 15) >> 4;
        if (ntile == 0) continue;
        const uint2* seg = recs + (size_t)b * CAP_X;

        // B frags, column-permuted: acc0 -> ch 2*col, acc1 -> ch 2*col+1
        const float* wk = wkern + (size_t)k * (INC * OUTC);
        bf16x8 b0, b1;
#pragma unroll
        for (int j = 0; j < 8; ++j) {
            const int kx = quad * 8 + j;
            const float2 w2 = *(const float2*)(wk + kx * OUTC + 2 * col);
            b0[j] = (__bf16)w2.x;
            b1[j] = (__bf16)w2.y;
        }

        while (true) {
            int t0 = 0;
            if (lane == 0) t0 = (int)atomicAdd(cursor + (size_t)b * CTR_STRIDE, 8u);
            t0 = __shfl(t0, 0);
            if (t0 >= ntile) break;
            const int tend = min(t0 + 8, ntile);
            for (int t = t0; t < tend; ++t) {
                const int s = t << 4;
                const uint2 myrec = seg[s + col];
                const unsigned ii = ((s + col) < cnt) ? myrec.x : 0u;

                bf16x8 a;
                if constexpr (BF16F) {
                    a = *(const bf16x8*)(fbf + (size_t)ii * INC + quad * 8);
                } else {
                    const float4* ap = (const float4*)(feats + (size_t)ii * INC + quad * 8);
                    const float4 alo = ap[0], ahi = ap[1];
                    a[0] = (__bf16)alo.x; a[1] = (__bf16)alo.y;
                    a[2] = (__bf16)alo.z; a[3] = (__bf16)alo.w;
                    a[4] = (__bf16)ahi.x; a[5] = (__bf16)ahi.y;
                    a[6] = (__bf16)ahi.z; a[7] = (__bf16)ahi.w;
                }

                const uint4 r01 = *(const uint4*)(seg + s + quad * 4);
                const uint4 r23 = *(const uint4*)(seg + s + quad * 4 + 2);

                f32x4 acc0 = {0.f, 0.f, 0.f, 0.f};
                f32x4 acc1 = {0.f, 0.f, 0.f, 0.f};
                acc0 = __builtin_amdgcn_mfma_f32_16x16x32_bf16(a, b0, acc0, 0, 0, 0);
                acc1 = __builtin_amdgcn_mfma_f32_16x16x32_bf16(a, b1, acc1, 0, 0, 0);

                const unsigned orw[4] = { r01.y, r01.w, r23.y, r23.w };
#pragma unroll
                for (int r = 0; r < 4; ++r) {
                    const float v0 = fminf(fmaxf(acc0[r], -64.f), 64.f);
                    const float v1 = fminf(fmaxf(acc1[r], -64.f), 64.f);
                    const int q0 = __float2int_rn(v0 * 256.0f);
                    const int q1 = __float2int_rn(v1 * 256.0f);
                    const int sr = q0 + (int)((unsigned)q1 << 16);
                    const int other = __shfl_xor(sr, 1);
                    if (((r & 1) == par) && (s + quad * 4 + r) < cnt) {
                        const int lo32 = par ? other : sr;   // ch 4w,4w+1
                        const int hi32 = par ? sr : other;   // ch 4w+2,4w+3
                        const unsigned long long C =
                            (unsigned long long)(long long)lo32 +
                            ((unsigned long long)(unsigned)hi32 << 32);
                        __hip_atomic_fetch_add(acc + (size_t)orw[r] * 8 + w, C,
                                               __ATOMIC_RELAXED,
                                               __HIP_MEMORY_SCOPE_WORKGROUP);
                    }
                }
            }
        }
    }
}

// Decode + BN + ReLU (verified in R4): one u64 word (4 channels) per thread.
__global__ __launch_bounds__(256) void bn_relu_decode(
    const unsigned long long* __restrict__ ws,
    float* __restrict__ out,
    const float* __restrict__ gamma,
    const float* __restrict__ beta,
    const float* __restrict__ mean,
    const float* __restrict__ var,
    int nwords)   // N*8
{
    const int tid    = blockIdx.x * blockDim.x + threadIdx.x;
    const int stride = gridDim.x * blockDim.x;
    const int wrd    = tid & 7;
    const int c0     = wrd * 4;

    float s[4], q[4];
#pragma unroll
    for (int j = 0; j < 4; ++j) {
        s[j] = gamma[c0 + j] * rsqrtf(var[c0 + j] + 1e-5f);
        q[j] = beta[c0 + j] - mean[c0 + j] * s[j];
    }

    float4* po = (float4*)out;
    for (int i = tid; i < nwords; i += stride) {
        long long t = (long long)ws[i];
        const int d0 = (int)(short)(t & 0xFFFF); t = (t - d0) >> 16;
        const int d1 = (int)(short)(t & 0xFFFF); t = (t - d1) >> 16;
        const int d2 = (int)(short)(t & 0xFFFF); t = (t - d2) >> 16;
        const int d3 = (int)t;
        float4 o4;
        o4.x = fmaxf(fmaf((float)d0 * (1.f / 256.f), s[0], q[0]), 0.f);
        o4.y = fmaxf(fmaf((float)d1 * (1.f / 256.f), s[1], q[1]), 0.f);
        o4.z = fmaxf(fmaf((float)d2 * (1.f / 256.f), s[2], q[2]), 0.f);
        o4.w = fmaxf(fmaf((float)d3 * (1.f / 256.f), s[3], q[3]), 0.f);
        po[i] = o4;
    }
}

// ------------------- pk-f16 atomic path (R3, 693us, fallback) ---------------
__global__ __launch_bounds__(256) void scatter_conv_mfma_pk(
    const float* __restrict__ feats,
    const float* __restrict__ wkern,
    const int*   __restrict__ in_idx,
    const int*   __restrict__ out_idx,
    __half2*     __restrict__ ws,
    int N)
{
    const int k    = blockIdx.y;
    const int lane = threadIdx.x & 63;
    const int col  = lane & 15;
    const int quad = lane >> 4;

    const int wave   = blockIdx.x * 4 + (threadIdx.x >> 6);
    const int nwaves = gridDim.x * 4;

    const float* wk = wkern + (size_t)k * (INC * OUTC);
    bf16x8 b0, b1;
#pragma unroll
    for (int j = 0; j < 8; ++j) {
        const int kk = quad * 8 + j;
        b0[j] = (__bf16)wk[kk * OUTC + 2 * col];
        b1[j] = (__bf16)wk[kk * OUTC + 2 * col + 1];
    }

    const int* iin_p  = in_idx  + (size_t)k * N;
    const int* iout_p = out_idx + (size_t)k * N;
    const int  ntiles = N >> 4;

    for (int t = wave; t < ntiles; t += nwaves) {
        const int base = t << 4;
        const int iin = iin_p[base + col];
        int orow[4];
#pragma unroll
        for (int r = 0; r < 4; ++r) orow[r] = iout_p[base + quad * 4 + r];

        const float4* ap = (const float4*)(feats + (size_t)iin * INC + quad * 8);
        const float4 a_lo = ap[0];
        const float4 a_hi = ap[1];
        bf16x8 a;
        a[0] = (__bf16)a_lo.x; a[1] = (__bf16)a_lo.y;
        a[2] = (__bf16)a_lo.z; a[3] = (__bf16)a_lo.w;
        a[4] = (__bf16)a_hi.x; a[5] = (__bf16)a_hi.y;
        a[6] = (__bf16)a_hi.z; a[7] = (__bf16)a_hi.w;

        f32x4 acc0 = {0.f, 0.f, 0.f, 0.f};
        f32x4 acc1 = {0.f, 0.f, 0.f, 0.f};
        acc0 = __builtin_amdgcn_mfma_f32_16x16x32_bf16(a, b0, acc0, 0, 0, 0);
        acc1 = __builtin_amdgcn_mfma_f32_16x16x32_bf16(a, b1, acc1, 0, 0, 0);

#pragma unroll
        for (int r = 0; r < 4; ++r) {
            __half2 v = __halves2half2(__float2half(acc0[r]), __float2half(acc1[r]));
            unsafeAtomicAdd(ws + (size_t)orow[r] * 16 + col, v);
        }
    }
}

__global__ __launch_bounds__(256) void bn_relu_f16(
    const __half2* __restrict__ ws,
    float* __restrict__ out,
    const float* __restrict__ gamma,
    const float* __restrict__ beta,
    const float* __restrict__ mean,
    const float* __restrict__ var,
    int total2)
{
    const int tid    = blockIdx.x * blockDim.x + threadIdx.x;
    const int stride = gridDim.x * blockDim.x;
    const int p      = tid & 15;
    const int c0     = 2 * p;

    float s0 = gamma[c0]     * rsqrtf(var[c0]     + 1e-5f);
    float s1 = gamma[c0 + 1] * rsqrtf(var[c0 + 1] + 1e-5f);
    float q0 = beta[c0]     - mean[c0]     * s0;
    float q1 = beta[c0 + 1] - mean[c0 + 1] * s1;

    float2* po = (float2*)out;
    for (int i = tid; i < total2; i += stride) {
        const __half2 h = ws[i];
        float2 v;
        v.x = fmaxf(fmaf(__low2float(h),  s0, q0), 0.0f);
        v.y = fmaxf(fmaf(__high2float(h), s1, q1), 0.0f);
        po[i] = v;
    }
}

// ------------------------- fp32 fallback (R2 path) -------------------------
__global__ __launch_bounds__(256) void scatter_conv_mfma_f32(
    const float* __restrict__ feats,
    const float* __restrict__ wkern,
    const int*   __restrict__ in_idx,
    const int*   __restrict__ out_idx,
    float*       __restrict__ out,
    int N)
{
    const int k    = blockIdx.y;
    const int lane = threadIdx.x & 63;
    const int col  = lane & 15;
    const int quad = lane >> 4;
    const int wave   = blockIdx.x * 4 + (threadIdx.x >> 6);
    const int nwaves = gridDim.x * 4;

    const float* wk = wkern + (size_t)k * (INC * OUTC);
    bf16x8 b0, b1;
#pragma unroll
    for (int j = 0; j < 8; ++j) {
        const int kk = quad * 8 + j;
        b0[j] = (__bf16)wk[kk * OUTC + col];
        b1[j] = (__bf16)wk[kk * OUTC + 16 + col];
    }

    const int* iin_p  = in_idx  + (size_t)k * N;
    const int* iout_p = out_idx + (size_t)k * N;
    const int  ntiles = N >> 4;

    for (int t = wave; t < ntiles; t += nwaves) {
        const int base = t << 4;
        const int iin = iin_p[base + col];
        int orow[4];
#pragma unroll
        for (int r = 0; r < 4; ++r) orow[r] = iout_p[base + quad * 4 + r];

        const float4* ap = (const float4*)(feats + (size_t)iin * INC + quad * 8);
        const float4 a_lo = ap[0];
        const float4 a_hi = ap[1];
        bf16x8 a;
        a[0] = (__bf16)a_lo.x; a[1] = (__bf16)a_lo.y;
        a[2] = (__bf16)a_lo.z; a[3] = (__bf16)a_lo.w;
        a[4] = (__bf16)a_hi.x; a[5] = (__bf16)a_hi.y;
        a[6] = (__bf16)a_hi.z; a[7] = (__bf16)a_hi.w;

        f32x4 acc0 = {0.f, 0.f, 0.f, 0.f};
        f32x4 acc1 = {0.f, 0.f, 0.f, 0.f};
        acc0 = __builtin_amdgcn_mfma_f32_16x16x32_bf16(a, b0, acc0, 0, 0, 0);
        acc1 = __builtin_amdgcn_mfma_f32_16x16x32_bf16(a, b1, acc1, 0, 0, 0);

#pragma unroll
        for (int r = 0; r < 4; ++r) {
            float* dst = out + (size_t)orow[r] * OUTC + col;
            unsafeAtomicAdd(dst,      acc0[r]);
            unsafeAtomicAdd(dst + 16, acc1[r]);
        }
    }
}

__global__ __launch_bounds__(256) void bn_relu_f32_inplace(
    float* __restrict__ out,
    const float* __restrict__ gamma,
    const float* __restrict__ beta,
    const float* __restrict__ mean,
    const float* __restrict__ var,
    int total4)
{
    const int tid    = blockIdx.x * blockDim.x + threadIdx.x;
    const int stride = gridDim.x * blockDim.x;
    const int c0     = (tid & 7) << 2;

    float s[4], b[4];
#pragma unroll
    for (int j = 0; j < 4; ++j) {
        const int c = c0 + j;
        s[j] = gamma[c] * rsqrtf(var[c] + 1e-5f);
        b[j] = beta[c] - mean[c] * s[j];
    }

    float4* p = (float4*)out;
    for (int i = tid; i < total4; i += stride) {
        float4 v = p[i];
        v.x = fmaxf(fmaf(v.x, s[0], b[0]), 0.0f);
        v.y = fmaxf(fmaf(v.y, s[1], b[1]), 0.0f);
        v.z = fmaxf(fmaf(v.z, s[2], b[2]), 0.0f);
        v.w = fmaxf(fmaf(v.w, s[3], b[3]), 0.0f);
        p[i] = v;
    }
}

extern "C" void kernel_launch(void* const* d_in, const int* in_sizes, int n_in,
                              void* d_out, int out_size, void* d_ws, size_t ws_size,
                              hipStream_t stream) {
    const float* feats   = (const float*)d_in[0];
    const float* wkern   = (const float*)d_in[1];
    const float* gamma   = (const float*)d_in[2];
    const float* beta    = (const float*)d_in[3];
    const float* mean    = (const float*)d_in[4];
    const float* var     = (const float*)d_in[5];
    const int*   in_idx  = (const int*)d_in[6];
    const int*   out_idx = (const int*)d_in[7];
    float*       out     = (float*)d_out;

    const int N = in_sizes[0] / INC;                  // 400000
    const int K = in_sizes[1] / (INC * OUTC);         // 27
    const int slice = (N + 7) / 8;

    const int nb = K * 8;                             // 216 buckets
    const size_t ctr_b  = (size_t)nb * CTR_STRIDE * 4;
    const size_t meta_b = ((2 * ctr_b) + 4095) & ~(size_t)4095;
    const size_t acc_b  = (size_t)N * 8 * 8;          // 25.6 MB u64 digits
    const size_t fbf_b  = (size_t)N * INC * 2;        // 25.6 MB bf16 feats
    const size_t rec_b  = (size_t)nb * CAP_X * 8;     // 90.2 MB records
    const size_t need1  = meta_b + acc_b + fbf_b + rec_b;  // ~141.5 MB
    const size_t need2  = meta_b + acc_b + rec_b;          // ~115.9 MB
    const size_t need_pk = (size_t)N * OUTC * sizeof(__half);

    if (ws_size >= need2 && N <= (1 << 19)) {
        char* base = (char*)d_ws;
        unsigned* head   = (unsigned*)base;
        unsigned* cursor = (unsigned*)(base + ctr_b);
        unsigned long long* acc = (unsigned long long*)(base + meta_b);
        hipMemsetAsync(base, 0, meta_b + acc_b, stream);
        if (ws_size >= need1) {
            __bf16* fbf = (__bf16*)(base + meta_b + acc_b);
            uint2*  recs = (uint2*)(base + meta_b + acc_b + fbf_b);
            prep_feats<<<768, 256, 0, stream>>>(feats, fbf, N * 4);
            fill_xcd<<<dim3(96, K), 256, 0, stream>>>(in_idx, out_idx, head, recs, N, slice);
            conv_xcd<true><<<1024, 256, 0, stream>>>(
                feats, fbf, wkern, head, cursor, recs, acc, N, K);
        } else {
            uint2* recs = (uint2*)(base + meta_b + acc_b);
            fill_xcd<<<dim3(96, K), 256, 0, stream>>>(in_idx, out_idx, head, recs, N, slice);
            conv_xcd<false><<<1024, 256, 0, stream>>>(
                feats, nullptr, wkern, head, cursor, recs, acc, N, K);
        }
        bn_relu_decode<<<1024, 256, 0, stream>>>(acc, out, gamma, beta, mean, var, N * 8);
    } else if (ws_size >= need_pk) {
        __half2* acc = (__half2*)d_ws;
        hipMemsetAsync(acc, 0, need_pk, stream);
        dim3 grid(80, K);
        scatter_conv_mfma_pk<<<grid, 256, 0, stream>>>(
            feats, wkern, in_idx, out_idx, acc, N);
        bn_relu_f16<<<1024, 256, 0, stream>>>(acc, out, gamma, beta, mean, var, N * 16);
    } else {
        hipMemsetAsync(out, 0, (size_t)out_size * sizeof(float), stream);
        dim3 grid(80, K);
        scatter_conv_mfma_f32<<<grid, 256, 0, stream>>>(
            feats, wkern, in_idx, out_idx, out, N);
        bn_relu_f32_inplace<<<1024, 256, 0, stream>>>(
            out, gamma, beta, mean, var, out_size / 4);
    }
}